// Round 11
// baseline (124.021 us; speedup 1.0000x reference)
//
#include <hip/hip_runtime.h>
#include <math.h>
#include <stdint.h>

#define BB 4
#define TT 4096
#define HH 16
#define DD 64
#define GG 64
#define NRND 192
#define HD 1024          // HH*DD
#define NBH 64           // BB*HH
#define NCHUNK 4         // key-chunks for the global part (16 tiles each)
#define NGBLK (NBH*NCHUNK)   // 256 global-chunk blocks
#define NSPB  (NBH*63)       // 4032 sparse blocks

// ---- workspace layout (bytes) ----
// Kbf: bf16 K  tile-blocked [bh][tile64][c=d-chunk][tok][16B]
// Vt : bf16 V^T tile-blocked [bh][tile64][c=tok-chunk][d][16B]
// Krt/Vrt: same 8KB-tile format, pre-gathered random tokens (3 tiles per bh)
#define OFF_KBF  0ull
#define OFF_VT   33554432ull
#define OFF_KRT  67108864ull
#define OFF_VRT  68681728ull
#define OFF_WACC 70254592ull   // fp32 [256][4096]
#define OFF_WM   74448896ull   // fp32 [256][64]
#define OFF_WL   74514432ull   // fp32 [256][64]

typedef __attribute__((ext_vector_type(8))) short short8;
typedef __attribute__((ext_vector_type(16))) float f32x16;

__device__ __forceinline__ ushort rne_u(float f) {
    uint32_t u = __builtin_bit_cast(uint32_t, f);
    u += 0x7fffu + ((u >> 16) & 1u);
    return (ushort)(u >> 16);
}
__device__ __forceinline__ short bf_trunc_s(float f) {
    uint32_t u = __builtin_bit_cast(uint32_t, f);
    return (short)(u >> 16);
}
__device__ __forceinline__ float bf_back(short s) {
    uint32_t u = ((uint32_t)(uint16_t)s) << 16;
    return __builtin_bit_cast(float, u);
}
// raw v_exp_f32 (2^x) — avoid __ocml_exp2_f32 slow-path expansion
__device__ __forceinline__ float exp2_fast(float x) {
    float r; asm("v_exp_f32 %0, %1" : "=v"(r) : "v"(x)); return r;
}
// 16B from LDS at 8B alignment
__device__ __forceinline__ short8 ld8u(const ushort* p) {
    typedef __attribute__((ext_vector_type(4))) short short4v;
    short4v a = *(const short4v*)p;
    short4v b = *(const short4v*)(p + 4);
    short8 r;
    r[0]=a[0]; r[1]=a[1]; r[2]=a[2]; r[3]=a[3];
    r[4]=b[0]; r[5]=b[1]; r[6]=b[2]; r[7]=b[3];
    return r;
}

// async global->LDS, 16B/lane; LDS dest = wave-uniform base + lane*16
typedef const __attribute__((address_space(1))) uint32_t* gas1_t;
typedef __attribute__((address_space(3))) uint32_t* las3_t;
__device__ __forceinline__ void gld16(const void* g, void* l) {
    __builtin_amdgcn_global_load_lds((gas1_t)g, (las3_t)l, 16, 0, 0);
}

// ============================================================================
// Prep: tile-block K (bf16) and V^T (bf16) per (b,h); pre-gather random tiles.
// ============================================================================
__global__ __launch_bounds__(256, 4)
void bb_prep(const float* __restrict__ K, const float* __restrict__ V,
             const int* __restrict__ RIDX, char* __restrict__ ws)
{
    __shared__ ushort tl[64][68];
    __shared__ int toks[NRND];
    const int bid = blockIdx.x, tid = threadIdx.x;
    const int r  = tid >> 2;
    const int d0 = (tid & 3) * 16;

    if (bid < 8192) {
        const bool isK = bid < 4096;
        const int id = isK ? bid : bid - 4096;
        const int bh = id >> 6, tile = id & 63;
        const int b = bh >> 4, h = bh & 15;
        const float* src = (isK ? K : V) + ((size_t)b*TT*HH + h)*DD
                         + (size_t)(tile*64 + r)*HD + d0;
        float f[16];
        #pragma unroll
        for (int i = 0; i < 16; i += 4) {
            const float4 v4 = *(const float4*)(src + i);
            f[i]=v4.x; f[i+1]=v4.y; f[i+2]=v4.z; f[i+3]=v4.w;
        }
        if (isK) {
            #pragma unroll
            for (int i = 0; i < 16; ++i) tl[r][d0+i] = rne_u(f[i]);     // [tok][d]
        } else {
            #pragma unroll
            for (int i = 0; i < 16; ++i) tl[d0+i][r] = rne_u(f[i]);     // [d][tok]
        }
        __syncthreads();
        char* obase = ws + (isK ? OFF_KBF : OFF_VT)
                    + (size_t)bh*524288 + (size_t)tile*8192;
        #pragma unroll
        for (int e = 0; e < 2; ++e) {
            const int uu = tid*2 + e;
            const int c = uu >> 6, rr = uu & 63;
            *(short8*)(obase + c*1024 + rr*16) = ld8u(&tl[rr][c*8]);
        }
    } else {
        // ---- random-token gather: 3 K-tiles + 3 V-tiles per bh ----
        const int bh = bid - 8192;
        const int b = bh >> 4, h = bh & 15;
        const size_t base = ((size_t)b*TT*HH + h)*DD;
        if (tid < NRND) toks[tid] = RIDX[tid];
        __syncthreads();
        for (int sub = 0; sub < 3; ++sub) {
            const int tok = toks[sub*64 + r];
            float f[16];
            const float* ks = K + base + (size_t)tok*HD + d0;
            #pragma unroll
            for (int i = 0; i < 16; i += 4) {
                const float4 v4 = *(const float4*)(ks + i);
                f[i]=v4.x; f[i+1]=v4.y; f[i+2]=v4.z; f[i+3]=v4.w;
            }
            #pragma unroll
            for (int i = 0; i < 16; ++i) tl[r][d0+i] = rne_u(f[i]);
            __syncthreads();
            {
                char* obase = ws + OFF_KRT + (size_t)bh*24576 + (size_t)sub*8192;
                #pragma unroll
                for (int e = 0; e < 2; ++e) {
                    const int uu = tid*2 + e;
                    const int c = uu >> 6, rr = uu & 63;
                    *(short8*)(obase + c*1024 + rr*16) = ld8u(&tl[rr][c*8]);
                }
            }
            __syncthreads();
            const float* vs = V + base + (size_t)tok*HD + d0;
            #pragma unroll
            for (int i = 0; i < 16; i += 4) {
                const float4 v4 = *(const float4*)(vs + i);
                f[i]=v4.x; f[i+1]=v4.y; f[i+2]=v4.z; f[i+3]=v4.w;
            }
            #pragma unroll
            for (int i = 0; i < 16; ++i) tl[d0+i][r] = rne_u(f[i]);
            __syncthreads();
            {
                char* obase = ws + OFF_VRT + (size_t)bh*24576 + (size_t)sub*8192;
                #pragma unroll
                for (int e = 0; e < 2; ++e) {
                    const int uu = tid*2 + e;
                    const int c = uu >> 6, rr = uu & 63;
                    *(short8*)(obase + c*1024 + rr*16) = ld8u(&tl[rr][c*8]);
                }
            }
            __syncthreads();
        }
    }
}

// ============================================================================
// Main: BARRIER-FREE k-loop flash attention.
// Each wave dup-stages its own 4KB K-half into a private LDS dbuf region
// (sync = its own vmcnt only); V fragments read directly from pre-blocked ws
// (coalesced 16B/lane, issued under softmax). Waves fully decoupled; barriers
// only in the output-merge epilogue.
// ============================================================================
__global__ __launch_bounds__(256, 4)
void bb_mfma(const float* __restrict__ Q, float* __restrict__ OUT,
             char* __restrict__ ws)
{
    __shared__ __align__(16) char smem[32768];   // 4 waves x [2 bufs x 4KB]
    // epilogue aliases (k-loop data dead after post-loop barrier):
    float (*osum)[67] = (float(*)[67])smem;                  // 17152 B
    float* sm_m0 = (float*)(smem + 17408);                   // [64]
    float* sm_m1 = (float*)(smem + 17664);
    float* sm_l0 = (float*)(smem + 17920);
    float* sm_l1 = (float*)(smem + 18176);

    const int tid  = threadIdx.x;
    const int lane = tid & 63;
    const int wid  = tid >> 6;
    const int wq   = wid >> 1;      // q-half
    const int wk   = wid & 1;       // key-half
    const int lq   = lane & 31;
    const int lh   = lane >> 5;

    char* wbase = smem + wid*8192;                 // this wave's K region
    const int ksrc_lane = lh*1024 + wk*512 + lq*16;  // per-lane K src offset
    const int kld_lane  = lh*512 + lq*16;            // per-lane K LDS read offset

    // ---- XCD-aware remap: bh -> fixed XCD (= bh % 8) ----
    const int j = blockIdx.x;
    const bool is_glob = j < NGBLK;
    int bh, qtok0, ntiles, kt0 = 0, chunk = 0;
    if (is_glob) {
        chunk = j >> 6;                        // 0..3
        bh    = (j & 7) + 8 * ((j >> 3) & 7);
        kt0   = chunk * 16;
        qtok0 = 0; ntiles = 16;
    } else {
        const int js = j - NGBLK;
        bh    = (js & 7) + 8 * ((js >> 3) & 7);
        qtok0 = GG + (js >> 6) * 64;
        ntiles = 5;
    }
    const int b  = bh >> 4;
    const int hd = bh & 15;
    const size_t bh_off = ((size_t)b * TT * HH + hd) * DD;

    const char* kbf_bh = ws + OFF_KBF + (size_t)bh * 524288;
    const char* vt_bh  = ws + OFF_VT  + (size_t)bh * 524288;
    const char* krt_bh = ws + OFF_KRT + (size_t)bh * 24576;
    const char* vrt_bh = ws + OFF_VRT + (size_t)bh * 24576;

    auto kbase = [&](int kt) -> const char* {
        if (is_glob)     return kbf_bh + (size_t)(kt0 + kt) * 8192;
        if (kt == 0)     return kbf_bh + (size_t)(qtok0 >> 6) * 8192;
        if (kt == 1)     return kbf_bh;
        return krt_bh + (size_t)(kt - 2) * 8192;
    };
    auto vbase = [&](int kt) -> const char* {
        if (is_glob)     return vt_bh + (size_t)(kt0 + kt) * 8192;
        if (kt == 0)     return vt_bh + (size_t)(qtok0 >> 6) * 8192;
        if (kt == 1)     return vt_bh;
        return vrt_bh + (size_t)(kt - 2) * 8192;
    };

    // ---- Q raw loads ----
    float4 qa[4], qb[4];
    {
        const float* qp = Q + bh_off + (size_t)(qtok0 + wq*32 + lq) * HD;
        #pragma unroll
        for (int ks = 0; ks < 4; ++ks) {
            qa[ks] = *(const float4*)(qp + ks*16 + lh*8);
            qb[ks] = *(const float4*)(qp + ks*16 + lh*8 + 4);
        }
    }

    // ---- per-wave K stager: 4 gld16 into private region (dup across wq) ----
    auto stageK = [&](int buf, int kt_t) {
        const char* kb = kbase(kt_t);
        #pragma unroll
        for (int i = 0; i < 4; ++i)
            gld16(kb + i*2048 + ksrc_lane, wbase + buf*4096 + i*1024);
    };
    stageK(0, 0);

    // ---- Q fragments (hi/lo split), scale 0.125*log2(e) folded in ----
    const float QSC = 0.18033688f;
    short8 qfh[4], qfl[4];
    #pragma unroll
    for (int ks = 0; ks < 4; ++ks) {
        float fv[8] = {qa[ks].x, qa[ks].y, qa[ks].z, qa[ks].w,
                       qb[ks].x, qb[ks].y, qb[ks].z, qb[ks].w};
        #pragma unroll
        for (int jj = 0; jj < 8; ++jj) {
            const float x = fv[jj] * QSC;
            const short hi = bf_trunc_s(x);
            qfh[ks][jj] = hi;
            qfl[ks][jj] = bf_trunc_s(x - bf_back(hi));
        }
    }

    f32x16 acc0, acc1;
    #pragma unroll
    for (int r = 0; r < 16; ++r) { acc0[r] = 0.f; acc1[r] = 0.f; }
    float m_run = -INFINITY, l_run = 0.f;

    const int cb0 = (wk*4 + lh) * 1024;        // V chunk byte offsets
    const int cb1 = (wk*4 + 2 + lh) * 1024;

    for (int kt = 0; kt < ntiles; ++kt) {
        const int cur = kt & 1;
        if (kt + 1 < ntiles) {
            stageK(cur ^ 1, kt + 1);
            asm volatile("s_waitcnt vmcnt(4)" ::: "memory");  // this wave's tile-kt K done
        } else {
            asm volatile("s_waitcnt vmcnt(0)" ::: "memory");
        }

        // ---- QK: S^T tile [32 keys][32 q] in exp2 domain (private LDS) ----
        const char* kb = wbase + cur*4096;
        f32x16 sc;
        #pragma unroll
        for (int r = 0; r < 16; ++r) sc[r] = 0.f;
        {
            __builtin_amdgcn_s_setprio(1);
            #pragma unroll
            for (int ks = 0; ks < 4; ++ks) {
                const short8 ak = *(const short8*)(kb + ks*1024 + kld_lane);
                sc = __builtin_amdgcn_mfma_f32_32x32x16_bf16(ak, qfh[ks], sc, 0, 0, 0);
                sc = __builtin_amdgcn_mfma_f32_32x32x16_bf16(ak, qfl[ks], sc, 0, 0, 0);
            }
            __builtin_amdgcn_s_setprio(0);
        }

        // ---- V fragments direct from global (coalesced 16B/lane; hide under softmax) ----
        const char* vb = vbase(kt);
        const short8 vf0 = *(const short8*)(vb + cb0 + lq*16);
        const short8 vf1 = *(const short8*)(vb + cb0 + (lq + 32)*16);
        const short8 vf2 = *(const short8*)(vb + cb1 + lq*16);
        const short8 vf3 = *(const short8*)(vb + cb1 + (lq + 32)*16);

        // ---- online softmax (exp2 domain, wk-halves independent, defer-max) ----
        float pm = sc[0];
        #pragma unroll
        for (int r = 1; r < 16; ++r) pm = fmaxf(pm, sc[r]);
        pm = fmaxf(pm, __shfl_xor(pm, 32));
        if (__any(pm > m_run + 11.5f)) {       // ~e^8 headroom for bf16 P
            const float mnew = fmaxf(m_run, pm);
            const float cf = exp2_fast(m_run - mnew);
            l_run *= cf;
            #pragma unroll
            for (int r = 0; r < 16; ++r) { acc0[r] *= cf; acc1[r] *= cf; }
            m_run = mnew;
        }
        float ls = 0.f;
        #pragma unroll
        for (int r = 0; r < 16; ++r) {
            sc[r] = exp2_fast(sc[r] - m_run);   // P in-place
            ls += sc[r];
        }
        ls += __shfl_xor(ls, 32);
        l_run += ls;

        // ---- PV: out^T += V^T · P^T ; P packed via cvt_pk + permlane32_swap ----
        #pragma unroll
        for (int s = 0; s < 2; ++s) {
            uint32_t a01, a23, a45, a67;
            asm("v_cvt_pk_bf16_f32 %0, %1, %2" : "=v"(a01) : "v"(sc[8*s+0]), "v"(sc[8*s+1]));
            asm("v_cvt_pk_bf16_f32 %0, %1, %2" : "=v"(a23) : "v"(sc[8*s+2]), "v"(sc[8*s+3]));
            asm("v_cvt_pk_bf16_f32 %0, %1, %2" : "=v"(a45) : "v"(sc[8*s+4]), "v"(sc[8*s+5]));
            asm("v_cvt_pk_bf16_f32 %0, %1, %2" : "=v"(a67) : "v"(sc[8*s+6]), "v"(sc[8*s+7]));
            asm("v_permlane32_swap_b32 %0, %1" : "+v"(a01), "+v"(a45));
            asm("v_permlane32_swap_b32 %0, %1" : "+v"(a23), "+v"(a67));
            union { uint32_t u[4]; short8 v; } pfu;
            pfu.u[0] = a01; pfu.u[1] = a23; pfu.u[2] = a45; pfu.u[3] = a67;
            const short8 va  = (s == 0) ? vf0 : vf2;
            const short8 vbb = (s == 0) ? vf1 : vf3;
            __builtin_amdgcn_s_setprio(1);
            acc0 = __builtin_amdgcn_mfma_f32_32x32x16_bf16(va,  pfu.v, acc0, 0, 0, 0);
            acc1 = __builtin_amdgcn_mfma_f32_32x32x16_bf16(vbb, pfu.v, acc1, 0, 0, 0);
            __builtin_amdgcn_s_setprio(0);
        }
    }

    // ---- epilogue: merge wk halves (independent m), transpose via LDS ----
    __syncthreads();                            // waves may alias k-loop LDS now
    const int qrow = wq*32 + lq;
    if (lane < 32) {
        (wk ? sm_m1 : sm_m0)[qrow] = m_run;
        (wk ? sm_l1 : sm_l0)[qrow] = l_run;
    }
    __syncthreads();
    const float Mq  = fmaxf(sm_m0[qrow], sm_m1[qrow]);
    const float wsc = exp2_fast(m_run - Mq);
    if (wk == 0) {
        #pragma unroll
        for (int r = 0; r < 16; ++r) {
            const int dr = (r & 3) + 8*(r >> 2) + 4*lh;
            osum[qrow][dr     ] = acc0[r] * wsc;
            osum[qrow][dr + 32] = acc1[r] * wsc;
        }
    }
    __syncthreads();
    if (wk == 1) {
        #pragma unroll
        for (int r = 0; r < 16; ++r) {
            const int dr = (r & 3) + 8*(r >> 2) + 4*lh;
            osum[qrow][dr     ] += acc0[r] * wsc;
            osum[qrow][dr + 32] += acc1[r] * wsc;
        }
    }
    __syncthreads();
    {
        const int q  = tid >> 2;
        const int d0 = (tid & 3) * 16;
        const float M     = fmaxf(sm_m0[q], sm_m1[q]);
        const float lcomb = exp2_fast(sm_m0[q] - M) * sm_l0[q]
                          + exp2_fast(sm_m1[q] - M) * sm_l1[q];
        if (is_glob) {
            float* WACC = (float*)(ws + OFF_WACC);
            float* WM   = (float*)(ws + OFF_WM);
            float* WL   = (float*)(ws + OFF_WL);
            const int slot = chunk * NBH + bh;
            float* dst = WACC + (size_t)slot * 4096 + q * 64 + d0;
            #pragma unroll
            for (int i = 0; i < 16; i += 4) {
                float4 o;
                o.x = osum[q][d0 + i    ];
                o.y = osum[q][d0 + i + 1];
                o.z = osum[q][d0 + i + 2];
                o.w = osum[q][d0 + i + 3];
                *(float4*)(dst + i) = o;
            }
            if ((tid & 3) == 0) {
                WM[slot * 64 + q] = M;
                WL[slot * 64 + q] = lcomb;
            }
        } else {
            const float inv = 1.f / lcomb;
            float* dst = OUT + bh_off + (size_t)(qtok0 + q) * HD + d0;
            #pragma unroll
            for (int i = 0; i < 16; i += 4) {
                float4 o;
                o.x = osum[q][d0 + i    ] * inv;
                o.y = osum[q][d0 + i + 1] * inv;
                o.z = osum[q][d0 + i + 2] * inv;
                o.w = osum[q][d0 + i + 3] * inv;
                *(float4*)(dst + i) = o;
            }
        }
    }
}

// Combine the NCHUNK flash partials for the 64 global query rows of each (b,h).
__global__ __launch_bounds__(256, 4)
void bb_combine(const char* __restrict__ ws, float* __restrict__ OUT)
{
    const int bh = blockIdx.x;
    const int b  = bh >> 4;
    const int hd = bh & 15;
    const size_t bh_off = ((size_t)b * TT * HH + hd) * DD;

    const float* WACC = (const float*)(ws + OFF_WACC);
    const float* WM   = (const float*)(ws + OFF_WM);
    const float* WL   = (const float*)(ws + OFF_WL);

    const int q  = threadIdx.x >> 2;
    const int d0 = (threadIdx.x & 3) * 16;

    float m[NCHUNK];
    float M = -INFINITY;
    #pragma unroll
    for (int c = 0; c < NCHUNK; ++c) {
        m[c] = WM[(c * NBH + bh) * 64 + q];
        M = fmaxf(M, m[c]);
    }
    float w[NCHUNK];
    float denom = 0.f;
    #pragma unroll
    for (int c = 0; c < NCHUNK; ++c) {
        w[c] = exp2_fast(m[c] - M);
        denom += w[c] * WL[(c * NBH + bh) * 64 + q];
    }
    const float inv = 1.f / denom;

    float* dst = OUT + bh_off + (size_t)q * HD + d0;
    #pragma unroll
    for (int i = 0; i < 16; i += 4) {
        float ox = 0.f, oy = 0.f, oz = 0.f, ow = 0.f;
        #pragma unroll
        for (int c = 0; c < NCHUNK; ++c) {
            const float4 a = *(const float4*)&WACC[(size_t)(c * NBH + bh) * 4096 + q * 64 + d0 + i];
            ox += w[c] * a.x; oy += w[c] * a.y;
            oz += w[c] * a.z; ow += w[c] * a.w;
        }
        float4 o; o.x = ox * inv; o.y = oy * inv; o.z = oz * inv; o.w = ow * inv;
        *(float4*)(dst + i) = o;
    }
}

extern "C" void kernel_launch(void* const* d_in, const int* in_sizes, int n_in,
                              void* d_out, int out_size, void* d_ws, size_t ws_size,
                              hipStream_t stream) {
    const float* Q    = (const float*)d_in[0];
    const float* K    = (const float*)d_in[1];
    const float* V    = (const float*)d_in[2];
    const int*   RIDX = (const int*)d_in[3];
    float* OUT = (float*)d_out;
    char*  ws  = (char*)d_ws;

    // 1) tile-block K/V into bf16 workspace (+ pre-gathered random tiles)
    hipLaunchKernelGGL(bb_prep, dim3(8192 + 64), dim3(256), 0, stream,
                       K, V, RIDX, ws);
    // 2) attention: 256 global-chunk blocks + 4032 sparse blocks (barrier-free loop)
    hipLaunchKernelGGL(bb_mfma, dim3(NGBLK + NSPB), dim3(256), 0, stream,
                       Q, OUT, ws);
    // 3) combine global partials (writes OUT rows [0,64) per (b,h))
    hipLaunchKernelGGL(bb_combine, dim3(NBH), dim3(256), 0, stream, ws, OUT);
}

// Round 12
// 111.308 us; speedup vs baseline: 1.1142x; 1.1142x over previous
//
#include <hip/hip_runtime.h>
#include <math.h>
#include <stdint.h>

#define BB 4
#define TT 4096
#define HH 16
#define DD 64
#define GG 64
#define NRND 192
#define HD 1024          // HH*DD
#define NBH 64           // BB*HH
#define NCHUNK 4         // key-chunks for the global part (16 tiles each)
#define NGBLK (NBH*NCHUNK)   // 256 global-chunk blocks
#define NSPB  (NBH*63)       // 4032 sparse blocks

// ---- workspace layout (bytes) ----
// Kbf: bf16 K  tile-blocked [bh][tile64][c=d-chunk][tok][16B]
// Vt : bf16 V^T tile-blocked [bh][tile64][c=tok-chunk][d][16B]
// Krt/Vrt: same 8KB-tile format, pre-gathered random tokens (3 tiles per bh)
#define OFF_KBF  0ull
#define OFF_VT   33554432ull
#define OFF_KRT  67108864ull
#define OFF_VRT  68681728ull
#define OFF_WACC 70254592ull   // fp32 [256][4096]
#define OFF_WM   74448896ull   // fp32 [256][64]
#define OFF_WL   74514432ull   // fp32 [256][64]

typedef __attribute__((ext_vector_type(8))) short short8;
typedef __attribute__((ext_vector_type(16))) float f32x16;

__device__ __forceinline__ ushort rne_u(float f) {
    uint32_t u = __builtin_bit_cast(uint32_t, f);
    u += 0x7fffu + ((u >> 16) & 1u);
    return (ushort)(u >> 16);
}
// raw v_exp_f32 (2^x) — avoid __ocml_exp2_f32 slow-path expansion
__device__ __forceinline__ float exp2_fast(float x) {
    float r; asm("v_exp_f32 %0, %1" : "=v"(r) : "v"(x)); return r;
}
// 16B from LDS at 8B alignment
__device__ __forceinline__ short8 ld8u(const ushort* p) {
    typedef __attribute__((ext_vector_type(4))) short short4v;
    short4v a = *(const short4v*)p;
    short4v b = *(const short4v*)(p + 4);
    short8 r;
    r[0]=a[0]; r[1]=a[1]; r[2]=a[2]; r[3]=a[3];
    r[4]=b[0]; r[5]=b[1]; r[6]=b[2]; r[7]=b[3];
    return r;
}

// async global->LDS, 16B/lane; LDS dest = wave-uniform base + lane*16
typedef const __attribute__((address_space(1))) uint32_t* gas1_t;
typedef __attribute__((address_space(3))) uint32_t* las3_t;
__device__ __forceinline__ void gld16(const void* g, void* l) {
    __builtin_amdgcn_global_load_lds((gas1_t)g, (las3_t)l, 16, 0, 0);
}

// ============================================================================
// Prep: tile-block K (bf16) and V^T (bf16) per (b,h); pre-gather random tiles.
// ============================================================================
__global__ __launch_bounds__(256, 4)
void bb_prep(const float* __restrict__ K, const float* __restrict__ V,
             const int* __restrict__ RIDX, char* __restrict__ ws)
{
    __shared__ ushort tl[64][68];
    __shared__ int toks[NRND];
    const int bid = blockIdx.x, tid = threadIdx.x;
    const int r  = tid >> 2;
    const int d0 = (tid & 3) * 16;

    if (bid < 8192) {
        const bool isK = bid < 4096;
        const int id = isK ? bid : bid - 4096;
        const int bh = id >> 6, tile = id & 63;
        const int b = bh >> 4, h = bh & 15;
        const float* src = (isK ? K : V) + ((size_t)b*TT*HH + h)*DD
                         + (size_t)(tile*64 + r)*HD + d0;
        float f[16];
        #pragma unroll
        for (int i = 0; i < 16; i += 4) {
            const float4 v4 = *(const float4*)(src + i);
            f[i]=v4.x; f[i+1]=v4.y; f[i+2]=v4.z; f[i+3]=v4.w;
        }
        if (isK) {
            #pragma unroll
            for (int i = 0; i < 16; ++i) tl[r][d0+i] = rne_u(f[i]);     // [tok][d]
        } else {
            #pragma unroll
            for (int i = 0; i < 16; ++i) tl[d0+i][r] = rne_u(f[i]);     // [d][tok]
        }
        __syncthreads();
        char* obase = ws + (isK ? OFF_KBF : OFF_VT)
                    + (size_t)bh*524288 + (size_t)tile*8192;
        #pragma unroll
        for (int e = 0; e < 2; ++e) {
            const int uu = tid*2 + e;
            const int c = uu >> 6, rr = uu & 63;
            *(short8*)(obase + c*1024 + rr*16) = ld8u(&tl[rr][c*8]);
        }
    } else {
        // ---- random-token gather: 3 K-tiles + 3 V-tiles per bh ----
        const int bh = bid - 8192;
        const int b = bh >> 4, h = bh & 15;
        const size_t base = ((size_t)b*TT*HH + h)*DD;
        if (tid < NRND) toks[tid] = RIDX[tid];
        __syncthreads();
        for (int sub = 0; sub < 3; ++sub) {
            const int tok = toks[sub*64 + r];
            float f[16];
            const float* ks = K + base + (size_t)tok*HD + d0;
            #pragma unroll
            for (int i = 0; i < 16; i += 4) {
                const float4 v4 = *(const float4*)(ks + i);
                f[i]=v4.x; f[i+1]=v4.y; f[i+2]=v4.z; f[i+3]=v4.w;
            }
            #pragma unroll
            for (int i = 0; i < 16; ++i) tl[r][d0+i] = rne_u(f[i]);
            __syncthreads();
            {
                char* obase = ws + OFF_KRT + (size_t)bh*24576 + (size_t)sub*8192;
                #pragma unroll
                for (int e = 0; e < 2; ++e) {
                    const int uu = tid*2 + e;
                    const int c = uu >> 6, rr = uu & 63;
                    *(short8*)(obase + c*1024 + rr*16) = ld8u(&tl[rr][c*8]);
                }
            }
            __syncthreads();
            const float* vs = V + base + (size_t)tok*HD + d0;
            #pragma unroll
            for (int i = 0; i < 16; i += 4) {
                const float4 v4 = *(const float4*)(vs + i);
                f[i]=v4.x; f[i+1]=v4.y; f[i+2]=v4.z; f[i+3]=v4.w;
            }
            #pragma unroll
            for (int i = 0; i < 16; ++i) tl[d0+i][r] = rne_u(f[i]);
            __syncthreads();
            {
                char* obase = ws + OFF_VRT + (size_t)bh*24576 + (size_t)sub*8192;
                #pragma unroll
                for (int e = 0; e < 2; ++e) {
                    const int uu = tid*2 + e;
                    const int c = uu >> 6, rr = uu & 63;
                    *(short8*)(obase + c*1024 + rr*16) = ld8u(&tl[rr][c*8]);
                }
            }
            __syncthreads();
        }
    }
}

// ============================================================================
// Main: flash attention over pre-blocked bf16 tiles (round-9 skeleton).
// Conflict-free [c][row] LDS, double-buffered, vmcnt(4) pipeline, fast exp2,
// setprio on MFMA clusters. Single rne-bf16 Q fragment (no hi/lo split):
// QK = 4 MFMAs/wave-tile, -16 VGPR.
// ============================================================================
__global__ __launch_bounds__(256, 4)
void bb_mfma(const float* __restrict__ Q, float* __restrict__ OUT,
             char* __restrict__ ws)
{
    __shared__ __align__(16) char smem[32768];   // K[2][8KB] | V[2][8KB]
    // epilogue aliases (k-loop data dead after post-loop barrier):
    float (*osum)[67] = (float(*)[67])smem;                  // 17152 B
    float* sm_m0 = (float*)(smem + 17408);                   // [64]
    float* sm_m1 = (float*)(smem + 17664);
    float* sm_l0 = (float*)(smem + 17920);
    float* sm_l1 = (float*)(smem + 18176);

    const int tid  = threadIdx.x;
    const int lane = tid & 63;
    const int wid  = tid >> 6;
    const int wq   = wid >> 1;      // q-half
    const int wk   = wid & 1;       // key-half
    const int lq   = lane & 31;
    const int lh   = lane >> 5;

    // ---- XCD-aware remap: bh -> fixed XCD (= bh % 8) ----
    const int j = blockIdx.x;
    const bool is_glob = j < NGBLK;
    int bh, qtok0, ntiles, kt0 = 0, chunk = 0;
    if (is_glob) {
        chunk = j >> 6;                        // 0..3
        bh    = (j & 7) + 8 * ((j >> 3) & 7);
        kt0   = chunk * 16;
        qtok0 = 0; ntiles = 16;
    } else {
        const int js = j - NGBLK;
        bh    = (js & 7) + 8 * ((js >> 3) & 7);
        qtok0 = GG + (js >> 6) * 64;
        ntiles = 5;
    }
    const int b  = bh >> 4;
    const int hd = bh & 15;
    const size_t bh_off = ((size_t)b * TT * HH + hd) * DD;

    const char* kbf_bh = ws + OFF_KBF + (size_t)bh * 524288;
    const char* vt_bh  = ws + OFF_VT  + (size_t)bh * 524288;
    const char* krt_bh = ws + OFF_KRT + (size_t)bh * 24576;
    const char* vrt_bh = ws + OFF_VRT + (size_t)bh * 24576;

    auto kbase = [&](int kt) -> const char* {
        if (is_glob)     return kbf_bh + (size_t)(kt0 + kt) * 8192;
        if (kt == 0)     return kbf_bh + (size_t)(qtok0 >> 6) * 8192;
        if (kt == 1)     return kbf_bh;
        return krt_bh + (size_t)(kt - 2) * 8192;
    };
    auto vbase = [&](int kt) -> const char* {
        if (is_glob)     return vt_bh + (size_t)(kt0 + kt) * 8192;
        if (kt == 0)     return vt_bh + (size_t)(qtok0 >> 6) * 8192;
        if (kt == 1)     return vt_bh;
        return vrt_bh + (size_t)(kt - 2) * 8192;
    };

    // ---- Q raw loads ----
    float4 qa[4], qb[4];
    {
        const float* qp = Q + bh_off + (size_t)(qtok0 + wq*32 + lq) * HD;
        #pragma unroll
        for (int ks = 0; ks < 4; ++ks) {
            qa[ks] = *(const float4*)(qp + ks*16 + lh*8);
            qb[ks] = *(const float4*)(qp + ks*16 + lh*8 + 4);
        }
    }

    // ---- stager: 4 contiguous-1KB gld16 per wave ----
    auto stage = [&](int buf, int kt_t) {
        const char* kb = kbase(kt_t);
        const char* vb = vbase(kt_t);
        #pragma unroll
        for (int i = 0; i < 2; ++i) {
            const int c = wid*2 + i;
            gld16(kb + c*1024 + lane*16, smem + buf*8192 + c*1024);
            gld16(vb + c*1024 + lane*16, smem + 16384 + buf*8192 + c*1024);
        }
    };
    stage(0, 0);

    // ---- Q fragment (single rne-bf16), scale 0.125*log2(e) folded in ----
    const float QSC = 0.18033688f;
    short8 qf[4];
    #pragma unroll
    for (int ks = 0; ks < 4; ++ks) {
        float fv[8] = {qa[ks].x, qa[ks].y, qa[ks].z, qa[ks].w,
                       qb[ks].x, qb[ks].y, qb[ks].z, qb[ks].w};
        #pragma unroll
        for (int jj = 0; jj < 8; ++jj)
            qf[ks][jj] = (short)rne_u(fv[jj] * QSC);
    }

    f32x16 acc0, acc1;
    #pragma unroll
    for (int r = 0; r < 16; ++r) { acc0[r] = 0.f; acc1[r] = 0.f; }
    float m_run = -INFINITY, l_run = 0.f;

    for (int kt = 0; kt < ntiles; ++kt) {
        const int cur = kt & 1;
        const bool hn = (kt + 1 < ntiles);
        if (hn) {
            stage(cur ^ 1, kt + 1);
            asm volatile("s_waitcnt vmcnt(4)" ::: "memory");
        } else {
            asm volatile("s_waitcnt vmcnt(0)" ::: "memory");
        }
        __builtin_amdgcn_s_barrier();
        asm volatile("" ::: "memory");

        const char* kb = smem + cur*8192;
        const char* vb = smem + 16384 + cur*8192;

        // ---- QK: S^T tile [32 keys][32 q] in exp2 domain ----
        f32x16 sc;
        #pragma unroll
        for (int r = 0; r < 16; ++r) sc[r] = 0.f;
        {
            const int krow = wk*32 + lq;
            __builtin_amdgcn_s_setprio(1);
            #pragma unroll
            for (int ks = 0; ks < 4; ++ks) {
                const short8 ak = *(const short8*)(kb + (ks*2 + lh)*1024 + krow*16);
                sc = __builtin_amdgcn_mfma_f32_32x32x16_bf16(ak, qf[ks], sc, 0, 0, 0);
            }
            __builtin_amdgcn_s_setprio(0);
        }

        // ---- online softmax (exp2 domain, wk-halves independent, defer-max) ----
        float pm = sc[0];
        #pragma unroll
        for (int r = 1; r < 16; ++r) pm = fmaxf(pm, sc[r]);
        pm = fmaxf(pm, __shfl_xor(pm, 32));
        if (__any(pm > m_run + 11.5f)) {       // ~e^8 headroom for bf16 P
            const float mnew = fmaxf(m_run, pm);
            const float cf = exp2_fast(m_run - mnew);
            l_run *= cf;
            #pragma unroll
            for (int r = 0; r < 16; ++r) { acc0[r] *= cf; acc1[r] *= cf; }
            m_run = mnew;
        }
        float ls = 0.f;
        #pragma unroll
        for (int r = 0; r < 16; ++r) {
            sc[r] = exp2_fast(sc[r] - m_run);   // P in-place
            ls += sc[r];
        }
        ls += __shfl_xor(ls, 32);
        l_run += ls;

        // ---- PV: out^T += V^T · P^T ; P packed via cvt_pk + permlane32_swap ----
        #pragma unroll
        for (int s = 0; s < 2; ++s) {
            uint32_t a01, a23, a45, a67;
            asm("v_cvt_pk_bf16_f32 %0, %1, %2" : "=v"(a01) : "v"(sc[8*s+0]), "v"(sc[8*s+1]));
            asm("v_cvt_pk_bf16_f32 %0, %1, %2" : "=v"(a23) : "v"(sc[8*s+2]), "v"(sc[8*s+3]));
            asm("v_cvt_pk_bf16_f32 %0, %1, %2" : "=v"(a45) : "v"(sc[8*s+4]), "v"(sc[8*s+5]));
            asm("v_cvt_pk_bf16_f32 %0, %1, %2" : "=v"(a67) : "v"(sc[8*s+6]), "v"(sc[8*s+7]));
            asm("v_permlane32_swap_b32 %0, %1" : "+v"(a01), "+v"(a45));
            asm("v_permlane32_swap_b32 %0, %1" : "+v"(a23), "+v"(a67));
            union { uint32_t u[4]; short8 v; } pfu;
            pfu.u[0] = a01; pfu.u[1] = a23; pfu.u[2] = a45; pfu.u[3] = a67;
            const int cb = wk*4 + s*2 + lh;    // token chunk 0..7
            const short8 v0 = *(const short8*)(vb + cb*1024 + lq*16);
            const short8 v1 = *(const short8*)(vb + cb*1024 + (lq + 32)*16);
            __builtin_amdgcn_s_setprio(1);
            acc0 = __builtin_amdgcn_mfma_f32_32x32x16_bf16(v0, pfu.v, acc0, 0, 0, 0);
            acc1 = __builtin_amdgcn_mfma_f32_32x32x16_bf16(v1, pfu.v, acc1, 0, 0, 0);
            __builtin_amdgcn_s_setprio(0);
        }

        if (hn) {                               // cur is restaged next iter
            asm volatile("" ::: "memory");
            __builtin_amdgcn_s_barrier();
            asm volatile("" ::: "memory");
        }
    }

    // ---- epilogue: merge wk halves (independent m), transpose via LDS ----
    __syncthreads();                            // k-loop LDS reads done (aliasing safe)
    const int qrow = wq*32 + lq;
    if (lane < 32) {
        (wk ? sm_m1 : sm_m0)[qrow] = m_run;
        (wk ? sm_l1 : sm_l0)[qrow] = l_run;
    }
    __syncthreads();
    const float Mq  = fmaxf(sm_m0[qrow], sm_m1[qrow]);
    const float wsc = exp2_fast(m_run - Mq);
    if (wk == 0) {
        #pragma unroll
        for (int r = 0; r < 16; ++r) {
            const int dr = (r & 3) + 8*(r >> 2) + 4*lh;
            osum[qrow][dr     ] = acc0[r] * wsc;
            osum[qrow][dr + 32] = acc1[r] * wsc;
        }
    }
    __syncthreads();
    if (wk == 1) {
        #pragma unroll
        for (int r = 0; r < 16; ++r) {
            const int dr = (r & 3) + 8*(r >> 2) + 4*lh;
            osum[qrow][dr     ] += acc0[r] * wsc;
            osum[qrow][dr + 32] += acc1[r] * wsc;
        }
    }
    __syncthreads();
    {
        const int q  = tid >> 2;
        const int d0 = (tid & 3) * 16;
        const float M     = fmaxf(sm_m0[q], sm_m1[q]);
        const float lcomb = exp2_fast(sm_m0[q] - M) * sm_l0[q]
                          + exp2_fast(sm_m1[q] - M) * sm_l1[q];
        if (is_glob) {
            float* WACC = (float*)(ws + OFF_WACC);
            float* WM   = (float*)(ws + OFF_WM);
            float* WL   = (float*)(ws + OFF_WL);
            const int slot = chunk * NBH + bh;
            float* dst = WACC + (size_t)slot * 4096 + q * 64 + d0;
            #pragma unroll
            for (int i = 0; i < 16; i += 4) {
                float4 o;
                o.x = osum[q][d0 + i    ];
                o.y = osum[q][d0 + i + 1];
                o.z = osum[q][d0 + i + 2];
                o.w = osum[q][d0 + i + 3];
                *(float4*)(dst + i) = o;
            }
            if ((tid & 3) == 0) {
                WM[slot * 64 + q] = M;
                WL[slot * 64 + q] = lcomb;
            }
        } else {
            const float inv = 1.f / lcomb;
            float* dst = OUT + bh_off + (size_t)(qtok0 + q) * HD + d0;
            #pragma unroll
            for (int i = 0; i < 16; i += 4) {
                float4 o;
                o.x = osum[q][d0 + i    ] * inv;
                o.y = osum[q][d0 + i + 1] * inv;
                o.z = osum[q][d0 + i + 2] * inv;
                o.w = osum[q][d0 + i + 3] * inv;
                *(float4*)(dst + i) = o;
            }
        }
    }
}

// Combine the NCHUNK flash partials for the 64 global query rows of each (b,h).
// 256 blocks x 64 threads (4 q-quarters per bh) -> all CUs busy.
__global__ __launch_bounds__(64, 8)
void bb_combine(const char* __restrict__ ws, float* __restrict__ OUT)
{
    const int bid = blockIdx.x;            // 0..255
    const int bh  = bid >> 2;
    const int qq  = bid & 3;
    const int b   = bh >> 4;
    const int hd  = bh & 15;
    const size_t bh_off = ((size_t)b * TT * HH + hd) * DD;

    const float* WACC = (const float*)(ws + OFF_WACC);
    const float* WM   = (const float*)(ws + OFF_WM);
    const float* WL   = (const float*)(ws + OFF_WL);

    const int tid = threadIdx.x;           // 0..63
    const int q  = qq * 16 + (tid >> 2);
    const int d0 = (tid & 3) * 16;

    float m[NCHUNK];
    float M = -INFINITY;
    #pragma unroll
    for (int c = 0; c < NCHUNK; ++c) {
        m[c] = WM[(c * NBH + bh) * 64 + q];
        M = fmaxf(M, m[c]);
    }
    float w[NCHUNK];
    float denom = 0.f;
    #pragma unroll
    for (int c = 0; c < NCHUNK; ++c) {
        w[c] = exp2_fast(m[c] - M);
        denom += w[c] * WL[(c * NBH + bh) * 64 + q];
    }
    const float inv = 1.f / denom;

    float* dst = OUT + bh_off + (size_t)q * HD + d0;
    #pragma unroll
    for (int i = 0; i < 16; i += 4) {
        float ox = 0.f, oy = 0.f, oz = 0.f, ow = 0.f;
        #pragma unroll
        for (int c = 0; c < NCHUNK; ++c) {
            const float4 a = *(const float4*)&WACC[(size_t)(c * NBH + bh) * 4096 + q * 64 + d0 + i];
            ox += w[c] * a.x; oy += w[c] * a.y;
            oz += w[c] * a.z; ow += w[c] * a.w;
        }
        float4 o; o.x = ox * inv; o.y = oy * inv; o.z = oz * inv; o.w = ow * inv;
        *(float4*)(dst + i) = o;
    }
}

extern "C" void kernel_launch(void* const* d_in, const int* in_sizes, int n_in,
                              void* d_out, int out_size, void* d_ws, size_t ws_size,
                              hipStream_t stream) {
    const float* Q    = (const float*)d_in[0];
    const float* K    = (const float*)d_in[1];
    const float* V    = (const float*)d_in[2];
    const int*   RIDX = (const int*)d_in[3];
    float* OUT = (float*)d_out;
    char*  ws  = (char*)d_ws;

    // 1) tile-block K/V into bf16 workspace (+ pre-gathered random tiles)
    hipLaunchKernelGGL(bb_prep, dim3(8192 + 64), dim3(256), 0, stream,
                       K, V, RIDX, ws);
    // 2) attention: 256 global-chunk blocks + 4032 sparse blocks
    hipLaunchKernelGGL(bb_mfma, dim3(NGBLK + NSPB), dim3(256), 0, stream,
                       Q, OUT, ws);
    // 3) combine global partials (writes OUT rows [0,64) per (b,h))
    hipLaunchKernelGGL(bb_combine, dim3(NBH * 4), dim3(64), 0, stream, ws, OUT);
}